// Round 17
// baseline (61.975 us; speedup 1.0000x reference)
//
#include <hip/hip_runtime.h>

#define NG 48
#define NT 6                    // 4 A tiles per axis (8 cells)
#define NTILES (NT * NT * NT)   // 216
#define NSEG 8                  // atom-slice segments
#define SCAP 384                // per-(tile,segment) capacity; hot lambda ~126
// ws layout:
//   [0,     20736)  int actc[3*216*8]   (count per (tile,seg), stored always)
//   [32768, +10.6M) float copies[3*216][NSEG][512]
#define COPIES_OFF 32768

__device__ __forceinline__ float type_r(int type) {
    return (type == 0) ? 1.7f : ((type == 1) ? 1.55f : 1.52f);
}

// Dispatch 1: one 256-thread block per (segment, tile, type).
//  scan:    block box-tests its 2048-atom slice against its tile's halo
//  compact: deterministic ballot-ordered placement into LDS
//  eval:    2 cells/thread, BRANCHLESS body (cndmask selects, no ballot, no
//           divergent branch) -> iterations independent -> pipelined/unrolled
//  store:   512 partials iff count>0; count stored unconditionally.
__global__ __launch_bounds__(256) void gather_scan(
    const float* __restrict__ vC, const float* __restrict__ vN,
    const float* __restrict__ vO, int* __restrict__ actc,
    float* __restrict__ copies, int natoms)
{
    const int type = blockIdx.y;
    const int s = blockIdx.x / NTILES;        // segment-major spread
    const int t = blockIdx.x - s * NTILES;
    const int lt = type * NTILES + t;
    const float r = type_r(type);
    const float* __restrict__ vecs = (type == 0) ? vC : ((type == 1) ? vN : vO);

    const int tx = t / (NT * NT);
    const int ty = (t / NT) % NT;
    const int tz = t % NT;

    const int tid  = threadIdx.x;
    const int wave = tid >> 6;                // 0..3
    const int lane = tid & 63;

    // tile acceptance box (superset of the exact d<1.5r support)
    const float bb  = 1.5f * r + 1e-3f;
    const float lox = 4.0f * tx - bb, hix = 4.0f * tx + 3.5f + bb;
    const float loy = 4.0f * ty - bb, hiy = 4.0f * ty + 3.5f + bb;
    const float loz = 4.0f * tz - bb, hiz = 4.0f * tz + 3.5f + bb;

    __shared__ float4 sa[SCAP];
    __shared__ int wtot[4];
    __shared__ int wbase[5];

    // ---- scan this block's atom slice ----
    const int slen = (natoms + NSEG - 1) / NSEG;     // 2048
    const int alo  = s * slen;
    const int ahi  = min(natoms, alo + slen);
    const int nr   = (ahi - alo + 255) >> 8;         // 8

    unsigned int accept = 0u;
    #pragma unroll 4
    for (int k = 0; k < nr; ++k) {
        const int a = alo + (k << 8) + tid;
        bool ok = false;
        if (a < ahi) {
            const float vx = vecs[3 * a + 0] + 23.5f;   // vec = raw + 24 - 0.5
            const float vy = vecs[3 * a + 1] + 23.5f;
            const float vz = vecs[3 * a + 2] + 23.5f;
            ok = (vx > lox) & (vx < hix) & (vy > loy) & (vy < hiy)
               & (vz > loz) & (vz < hiz);
        }
        accept |= (ok ? 1u : 0u) << k;
    }

    // ---- deterministic compaction ----
    int wcnt = 0;
    for (int k = 0; k < nr; ++k)
        wcnt += (int)__popcll(__ballot((accept >> k) & 1u));
    if (lane == 0) wtot[wave] = wcnt;
    __syncthreads();
    if (tid == 0) {
        int acc = 0;
        #pragma unroll
        for (int w = 0; w < 4; ++w) { wbase[w] = acc; acc += wtot[w]; }
        wbase[4] = acc;
    }
    __syncthreads();
    const int n = min(wbase[4], SCAP);

    if (tid == 0) actc[lt * NSEG + s] = n;     // unconditional count store

    if (n == 0) return;                         // inactive: nothing else

    int run = wbase[wave];
    for (int k = 0; k < nr; ++k) {
        const unsigned long long m = __ballot((accept >> k) & 1u);
        if ((accept >> k) & 1u) {
            const int pos = run + (int)__popcll(m & ((1ull << lane) - 1ull));
            if (pos < SCAP) {
                const int a = alo + (k << 8) + tid;
                sa[pos] = make_float4(vecs[3 * a + 0] + 23.5f,
                                      vecs[3 * a + 1] + 23.5f,
                                      vecs[3 * a + 2] + 23.5f, 0.0f);
            }
        }
        run += (int)__popcll(m);
    }
    __syncthreads();

    // ---- eval: 2 cells/thread (x, x+4); BRANCHLESS body ----
    const int lx = tid >> 6;           // 0..3
    const int ly = (tid >> 3) & 7;
    const int lz = tid & 7;

    const float r15sq = (1.5f * r) * (1.5f * r);
    const float rr    = r * r;
    const float E2    = 7.3890562f;
    const float c2a   = 4.0f / (E2 * rr);
    const float c2b   = 12.0f / (E2 * r);
    const float c2c   = 9.0f / E2;
    const float n2orr = -2.0f / rr;

    const float px0 = 0.5f * (float)(tx * 8 + lx);
    const float px1 = px0 + 2.0f;
    const float py  = 0.5f * (float)(ty * 8 + ly);
    const float pz  = 0.5f * (float)(tz * 8 + lz);

    float acc0 = 0.0f, acc1 = 0.0f;

    #pragma unroll 2
    for (int j = 0; j < n; ++j) {
        const float4 a = sa[j];               // one b128 LDS broadcast
        const float dy  = a.y - py;
        const float dz  = a.z - pz;
        const float syz = fmaf(dy, dy, dz * dz);
        const float dx0 = a.x - px0;
        const float dx1 = a.x - px1;
        const float d2a = fmaf(dx0, dx0, syz);
        const float d2b = fmaf(dx1, dx1, syz);
        const float da  = sqrtf(d2a);
        const float db  = sqrtf(d2b);
        const float f1a = __expf(n2orr * d2a);
        const float f1b = __expf(n2orr * d2b);
        const float f2a = fmaf(c2a, d2a, fmaf(-c2b, da, c2c));
        const float f2b = fmaf(c2a, d2b, fmaf(-c2b, db, c2c));
        const float va  = (da < r) ? f1a : f2a;        // cndmask
        const float vb  = (db < r) ? f1b : f2b;        // cndmask
        acc0 += (d2a < r15sq) ? va : 0.0f;             // cndmask + add
        acc1 += (d2b < r15sq) ? vb : 0.0f;
    }

    float* __restrict__ cp = copies + ((size_t)lt * NSEG + s) * 512;
    cp[tid]       = acc0;
    cp[tid + 256] = acc1;
}

// Dispatch 2: one block per (tile,type). Sum stored segments (count>0) in
// fixed order; write all 512 cells exactly once (zeros for inactive tiles).
__global__ __launch_bounds__(256) void reduce_kernel(
    const int* __restrict__ actc, const float* __restrict__ copies,
    float* __restrict__ out)
{
    const int type = blockIdx.y;
    const int t = blockIdx.x;
    const int lt = type * NTILES + t;
    const int tid = threadIdx.x;

    __shared__ int segn[NSEG];
    if (tid < NSEG) segn[tid] = actc[lt * NSEG + tid];
    __syncthreads();

    const float* __restrict__ cp = copies + ((size_t)lt * NSEG) * 512;
    float o0 = 0.0f, o1 = 0.0f;
    #pragma unroll
    for (int ss = 0; ss < NSEG; ++ss) {
        if (segn[ss] > 0) {
            o0 += cp[(size_t)ss * 512 + tid];
            o1 += cp[(size_t)ss * 512 + 256 + tid];
        }
    }

    const int tx = t / (NT * NT);
    const int ty = (t / NT) % NT;
    const int tz = t % NT;
    const int lx = tid >> 6;
    const int ly = (tid >> 3) & 7;
    const int lz = tid & 7;
    const int X0 = tx * 8 + lx;
    const int Y  = ty * 8 + ly;
    const int Z  = tz * 8 + lz;
    float* __restrict__ o = out + (size_t)type * NG * NG * NG;
    o[((X0      * NG) + Y) * NG + Z] = o0;
    o[(((X0 + 4) * NG) + Y) * NG + Z] = o1;
}

extern "C" void kernel_launch(void* const* d_in, const int* in_sizes, int n_in,
                              void* d_out, int out_size, void* d_ws, size_t ws_size,
                              hipStream_t stream) {
    const float* vC = (const float*)d_in[0];
    const float* vN = (const float*)d_in[1];
    const float* vO = (const float*)d_in[2];
    float* out = (float*)d_out;

    int* actc = (int*)d_ws;
    float* copies = (float*)((char*)d_ws + COPIES_OFF);

    const int natoms = in_sizes[0] / 3;   // 16384

    dim3 ggrid(NTILES * NSEG, 3, 1);
    gather_scan<<<ggrid, 256, 0, stream>>>(vC, vN, vO, actc, copies, natoms);

    dim3 rgrid(NTILES, 3, 1);
    reduce_kernel<<<rgrid, 256, 0, stream>>>(actc, copies, out);
}

// Round 18
// 43.003 us; speedup vs baseline: 1.4412x; 1.4412x over previous
//
#include <hip/hip_runtime.h>

#define NG 48
#define NT 6                    // 4 A tiles per axis (8 cells)
#define NTILES (NT * NT * NT)   // 216
#define NSEG 16                 // atom-slice segments
#define SCAP 192                // per-(tile,segment) capacity; hot lambda ~63
// ws layout:
//   [0,     41472)  int actc[3*216*16]  (count per (tile,seg), stored always)
//   [65536, +21.2M) float copies[3*216][NSEG][512]
#define COPIES_OFF 65536

__device__ __forceinline__ float type_r(int type) {
    return (type == 0) ? 1.7f : ((type == 1) ? 1.55f : 1.52f);
}

// Dispatch 1: one 128-thread block (2 waves) per (segment, tile, type).
//  scan:    block box-tests its 1024-atom slice against its tile's halo
//  compact: deterministic ballot-ordered placement into LDS
//  eval:    4 cells/thread (x,x+4)x(z,z+4) — one LDS broadcast + shared
//           sx/syz amortized over 4 cells; whole-wave miss cull + per-slot
//           branches (R17 proved unconditional transcendentals are 1.6x worse)
//  store:   512 partials iff count>0; count stored unconditionally.
__global__ __launch_bounds__(128) void gather_scan(
    const float* __restrict__ vC, const float* __restrict__ vN,
    const float* __restrict__ vO, int* __restrict__ actc,
    float* __restrict__ copies, int natoms)
{
    const int type = blockIdx.y;
    const int s = blockIdx.x / NTILES;        // segment-major spread
    const int t = blockIdx.x - s * NTILES;
    const int lt = type * NTILES + t;
    const float r = type_r(type);
    const float* __restrict__ vecs = (type == 0) ? vC : ((type == 1) ? vN : vO);

    const int tx = t / (NT * NT);
    const int ty = (t / NT) % NT;
    const int tz = t % NT;

    const int tid  = threadIdx.x;             // 0..127
    const int wave = tid >> 6;                // 0..1
    const int lane = tid & 63;

    // tile acceptance box (superset of the exact d<1.5r support)
    const float bb  = 1.5f * r + 1e-3f;
    const float lox = 4.0f * tx - bb, hix = 4.0f * tx + 3.5f + bb;
    const float loy = 4.0f * ty - bb, hiy = 4.0f * ty + 3.5f + bb;
    const float loz = 4.0f * tz - bb, hiz = 4.0f * tz + 3.5f + bb;

    __shared__ float4 sa[SCAP];
    __shared__ int wtot[2];
    __shared__ int wbase[3];

    // ---- scan this block's atom slice ----
    const int slen = (natoms + NSEG - 1) / NSEG;     // 1024
    const int alo  = s * slen;
    const int ahi  = min(natoms, alo + slen);
    const int nr   = (ahi - alo + 127) >> 7;         // 8

    unsigned int accept = 0u;
    for (int k = 0; k < nr; ++k) {
        const int a = alo + (k << 7) + tid;
        bool ok = false;
        if (a < ahi) {
            const float vx = vecs[3 * a + 0] + 23.5f;   // vec = raw + 24 - 0.5
            const float vy = vecs[3 * a + 1] + 23.5f;
            const float vz = vecs[3 * a + 2] + 23.5f;
            ok = (vx > lox) & (vx < hix) & (vy > loy) & (vy < hiy)
               & (vz > loz) & (vz < hiz);
        }
        accept |= (ok ? 1u : 0u) << k;
    }

    // ---- deterministic compaction ----
    int wcnt = 0;
    for (int k = 0; k < nr; ++k)
        wcnt += (int)__popcll(__ballot((accept >> k) & 1u));
    if (lane == 0) wtot[wave] = wcnt;
    __syncthreads();
    if (tid == 0) {
        wbase[0] = 0;
        wbase[1] = wtot[0];
        wbase[2] = wtot[0] + wtot[1];
    }
    __syncthreads();
    const int n = min(wbase[2], SCAP);

    if (tid == 0) actc[lt * NSEG + s] = n;     // unconditional count store

    if (n == 0) return;                         // inactive: nothing else

    int run = wbase[wave];
    for (int k = 0; k < nr; ++k) {
        const unsigned long long m = __ballot((accept >> k) & 1u);
        if ((accept >> k) & 1u) {
            const int pos = run + (int)__popcll(m & ((1ull << lane) - 1ull));
            if (pos < SCAP) {
                const int a = alo + (k << 7) + tid;
                sa[pos] = make_float4(vecs[3 * a + 0] + 23.5f,
                                      vecs[3 * a + 1] + 23.5f,
                                      vecs[3 * a + 2] + 23.5f, 0.0f);
            }
        }
        run += (int)__popcll(m);
    }
    __syncthreads();

    // ---- eval: 4 cells/thread (x,x+4)x(z,z+4); culled body ----
    const int lx = tid >> 5;                  // 0..3 -> x, x+4
    const int ly = (tid >> 2) & 7;            // 0..7
    const int lz = tid & 3;                   // 0..3 -> z, z+4

    const float r15sq = (1.5f * r) * (1.5f * r);
    const float rr    = r * r;
    const float E2    = 7.3890562f;
    const float c2a   = 4.0f / (E2 * rr);
    const float c2b   = 12.0f / (E2 * r);
    const float c2c   = 9.0f / E2;
    const float n2orr = -2.0f / rr;

    const float px0 = 0.5f * (float)(tx * 8 + lx);
    const float px1 = px0 + 2.0f;
    const float py  = 0.5f * (float)(ty * 8 + ly);
    const float pz0 = 0.5f * (float)(tz * 8 + lz);
    const float pz1 = pz0 + 2.0f;

    float acc00 = 0.0f, acc01 = 0.0f, acc10 = 0.0f, acc11 = 0.0f;

    for (int j = 0; j < n; ++j) {
        const float4 a = sa[j];               // one b128 LDS broadcast
        const float dy  = a.y - py;
        const float sy  = dy * dy;
        const float dz0 = a.z - pz0, dz1 = dz0 - 2.0f;
        const float sz0 = fmaf(dz0, dz0, sy), sz1 = fmaf(dz1, dz1, sy);
        const float dx0 = a.x - px0, dx1 = dx0 - 2.0f;
        const float xx0 = dx0 * dx0, xx1 = dx1 * dx1;
        const float d200 = xx0 + sz0, d201 = xx0 + sz1;
        const float d210 = xx1 + sz0, d211 = xx1 + sz1;
        const bool h00 = d200 < r15sq, h01 = d201 < r15sq;
        const bool h10 = d210 < r15sq, h11 = d211 < r15sq;
        if (__ballot(h00 | h01 | h10 | h11) == 0ull) continue;  // wave cull
        if (h00) { const float d = sqrtf(d200);
            acc00 += (d < r) ? __expf(n2orr * d200)
                             : fmaf(c2a, d200, fmaf(-c2b, d, c2c)); }
        if (h01) { const float d = sqrtf(d201);
            acc01 += (d < r) ? __expf(n2orr * d201)
                             : fmaf(c2a, d201, fmaf(-c2b, d, c2c)); }
        if (h10) { const float d = sqrtf(d210);
            acc10 += (d < r) ? __expf(n2orr * d210)
                             : fmaf(c2a, d210, fmaf(-c2b, d, c2c)); }
        if (h11) { const float d = sqrtf(d211);
            acc11 += (d < r) ? __expf(n2orr * d211)
                             : fmaf(c2a, d211, fmaf(-c2b, d, c2c)); }
    }

    // store: local cell = ((X*8)+Y)*8+Z, X=lx(+4), Y=ly, Z=lz(+4)
    float* __restrict__ cp = copies + ((size_t)lt * NSEG + s) * 512;
    cp[((lx      * 8) + ly) * 8 + lz]     = acc00;
    cp[((lx      * 8) + ly) * 8 + lz + 4] = acc01;
    cp[(((lx + 4) * 8) + ly) * 8 + lz]     = acc10;
    cp[(((lx + 4) * 8) + ly) * 8 + lz + 4] = acc11;
}

// Dispatch 2: one block per (tile,type). Sum stored segments (count>0) in
// fixed order; write all 512 cells exactly once (zeros for inactive tiles).
__global__ __launch_bounds__(256) void reduce_kernel(
    const int* __restrict__ actc, const float* __restrict__ copies,
    float* __restrict__ out)
{
    const int type = blockIdx.y;
    const int t = blockIdx.x;
    const int lt = type * NTILES + t;
    const int tid = threadIdx.x;

    __shared__ int segn[NSEG];
    if (tid < NSEG) segn[tid] = actc[lt * NSEG + tid];
    __syncthreads();

    const float* __restrict__ cp = copies + ((size_t)lt * NSEG) * 512;
    float o0 = 0.0f, o1 = 0.0f;
    #pragma unroll
    for (int ss = 0; ss < NSEG; ++ss) {
        if (segn[ss] > 0) {
            o0 += cp[(size_t)ss * 512 + tid];
            o1 += cp[(size_t)ss * 512 + 256 + tid];
        }
    }

    // cells tid and tid+256 in ((X*8)+Y)*8+Z layout
    const int tx = t / (NT * NT);
    const int ty = (t / NT) % NT;
    const int tz = t % NT;
    const int lx = tid >> 6;
    const int ly = (tid >> 3) & 7;
    const int lz = tid & 7;
    const int X0 = tx * 8 + lx;
    const int Y  = ty * 8 + ly;
    const int Z  = tz * 8 + lz;
    float* __restrict__ o = out + (size_t)type * NG * NG * NG;
    o[((X0      * NG) + Y) * NG + Z] = o0;
    o[(((X0 + 4) * NG) + Y) * NG + Z] = o1;
}

extern "C" void kernel_launch(void* const* d_in, const int* in_sizes, int n_in,
                              void* d_out, int out_size, void* d_ws, size_t ws_size,
                              hipStream_t stream) {
    const float* vC = (const float*)d_in[0];
    const float* vN = (const float*)d_in[1];
    const float* vO = (const float*)d_in[2];
    float* out = (float*)d_out;

    int* actc = (int*)d_ws;
    float* copies = (float*)((char*)d_ws + COPIES_OFF);

    const int natoms = in_sizes[0] / 3;   // 16384

    dim3 ggrid(NTILES * NSEG, 3, 1);
    gather_scan<<<ggrid, 128, 0, stream>>>(vC, vN, vO, actc, copies, natoms);

    dim3 rgrid(NTILES, 3, 1);
    reduce_kernel<<<rgrid, 256, 0, stream>>>(actc, copies, out);
}